// Round 2
// baseline (1212.607 us; speedup 1.0000x reference)
//
#include <hip/hip_runtime.h>
#include <math.h>

typedef __bf16 bf16_t;
typedef bf16_t bf16x8 __attribute__((ext_vector_type(8)));
typedef bf16_t bf16x2 __attribute__((ext_vector_type(2)));
typedef float f32x4 __attribute__((ext_vector_type(4)));

#define EMBED 2048
#define NHEADS 32
#define HDIM 64
#define MLP 8192
#define SEQ 1024
#define NTOK 2048      // B*S
#define QKV_N 6144

// async global->LDS, 16B per lane; LDS dest = wave-uniform base + lane*16
__device__ __forceinline__ void async_copy16(void* lds, const void* g) {
    __builtin_amdgcn_global_load_lds(
        (const __attribute__((address_space(1))) unsigned int*)g,
        (__attribute__((address_space(3))) unsigned int*)lds, 16, 0, 0);
}

// ---------------------------------------------------------------------------
// C = A(MxK,bf16) @ Bt(NxK,bf16)^T
// EPI=0: bf16 store
// EPI=1: fp32 store, acc + Res
// EPI=2: bf16 store, silu(Aux) * acc   (Aux bf16, same layout as C)
// 128x128 tile, BK=32, 4 waves, 16x16x32 bf16 MFMA (m97 structure)
// ---------------------------------------------------------------------------
template<int EPI>
__global__ __launch_bounds__(256) void gemm_bt(
    const bf16_t* __restrict__ A, const bf16_t* __restrict__ Bt,
    void* __restrict__ Cout, const float* __restrict__ Res,
    const bf16_t* __restrict__ Aux,
    int M, int N, int K)
{
    __shared__ __align__(16) bf16_t As[128 * 32];
    __shared__ __align__(16) bf16_t Bs[128 * 32];
    const int tid = threadIdx.x;
    const int wave = tid >> 6, lane = tid & 63;
    const int quad = lane >> 4, l15 = lane & 15;
    const int wr = wave >> 1, wc = wave & 1;
    const int m0 = blockIdx.x * 128, n0 = blockIdx.y * 128;
    const int srow = lane >> 2;            // 0..15 (row within 16-row chunk)
    const int scol = (lane & 3) * 8;       // elem offset within row

    f32x4 acc[4][4] = {};

    for (int k0 = 0; k0 < K; k0 += 32) {
        if (k0) __syncthreads();
#pragma unroll
        for (int s = 0; s < 2; ++s) {
            const int chunk = wave * 2 + s;          // 0..7, 16 rows each
            const int row = chunk * 16 + srow;
            async_copy16((char*)As + chunk * 1024,
                         A + (size_t)(m0 + row) * K + k0 + scol);
            async_copy16((char*)Bs + chunk * 1024,
                         Bt + (size_t)(n0 + row) * K + k0 + scol);
        }
        asm volatile("s_waitcnt vmcnt(0)" ::: "memory");
        __syncthreads();

        bf16x8 af[4], bfr[4];
#pragma unroll
        for (int i = 0; i < 4; ++i) {
            af[i]  = *(const bf16x8*)((const char*)As + (wr * 64 + i * 16 + l15) * 64 + quad * 16);
            bfr[i] = *(const bf16x8*)((const char*)Bs + (wc * 64 + i * 16 + l15) * 64 + quad * 16);
        }
#pragma unroll
        for (int i = 0; i < 4; ++i)
#pragma unroll
            for (int j = 0; j < 4; ++j)
                acc[i][j] = __builtin_amdgcn_mfma_f32_16x16x32_bf16(af[i], bfr[j], acc[i][j], 0, 0, 0);
    }

#pragma unroll
    for (int i = 0; i < 4; ++i) {
#pragma unroll
        for (int j = 0; j < 4; ++j) {
#pragma unroll
            for (int r = 0; r < 4; ++r) {
                const int row = m0 + wr * 64 + i * 16 + quad * 4 + r;
                const int col = n0 + wc * 64 + j * 16 + l15;
                const size_t idx = (size_t)row * N + col;
                if (EPI == 0) {
                    ((bf16_t*)Cout)[idx] = (bf16_t)acc[i][j][r];
                } else if (EPI == 1) {
                    ((float*)Cout)[idx] = Res[idx] + acc[i][j][r];
                } else {
                    const float g = (float)Aux[idx];
                    const float s = g / (1.0f + __expf(-g));
                    ((bf16_t*)Cout)[idx] = (bf16_t)(s * acc[i][j][r]);
                }
            }
        }
    }
}

// ---------------------------------------------------------------------------
// W (KxN fp32) -> Wt (NxK bf16), 32x32 LDS tiles
// ---------------------------------------------------------------------------
__global__ __launch_bounds__(256) void transpose_cvt(
    const float* __restrict__ src, bf16_t* __restrict__ dst, int K, int N)
{
    __shared__ float tile[32][33];
    const int tx = threadIdx.x & 31, ty = threadIdx.x >> 5;
    const int n0 = blockIdx.x * 32, k0 = blockIdx.y * 32;
#pragma unroll
    for (int i = 0; i < 4; ++i)
        tile[ty + 8 * i][tx] = src[(size_t)(k0 + ty + 8 * i) * N + n0 + tx];
    __syncthreads();
#pragma unroll
    for (int i = 0; i < 4; ++i)
        dst[(size_t)(n0 + ty + 8 * i) * K + k0 + tx] = (bf16_t)tile[tx][ty + 8 * i];
}

// ---------------------------------------------------------------------------
// RMSNorm: fp32 row (2048) -> bf16 row
// ---------------------------------------------------------------------------
__global__ __launch_bounds__(256) void rmsnorm_bf16(
    const float* __restrict__ x, const float* __restrict__ g, bf16_t* __restrict__ out)
{
    const int row = blockIdx.x;
    const int tid = threadIdx.x;
    const float* xr = x + (size_t)row * EMBED + tid * 8;
    const float4 a = *(const float4*)xr;
    const float4 b = *(const float4*)(xr + 4);
    float ss = a.x * a.x + a.y * a.y + a.z * a.z + a.w * a.w
             + b.x * b.x + b.y * b.y + b.z * b.z + b.w * b.w;
#pragma unroll
    for (int off = 1; off < 64; off <<= 1) ss += __shfl_xor(ss, off);
    __shared__ float red[4];
    if ((tid & 63) == 0) red[tid >> 6] = ss;
    __syncthreads();
    const float rs = rsqrtf((red[0] + red[1] + red[2] + red[3]) * (1.0f / EMBED) + 1e-5f);
    const float* gr = g + tid * 8;
    const float xv[8] = {a.x, a.y, a.z, a.w, b.x, b.y, b.z, b.w};
    bf16x8 o;
#pragma unroll
    for (int e = 0; e < 8; ++e) o[e] = (bf16_t)(xv[e] * rs * gr[e]);
    *(bf16x8*)(out + (size_t)row * EMBED + tid * 8) = o;
}

// ---------------------------------------------------------------------------
// RoPE in-place on q,k sections of qkv (token, 6144)
// ---------------------------------------------------------------------------
__global__ __launch_bounds__(256) void rope_qk(bf16_t* __restrict__ qkv)
{
    const int id = blockIdx.x * 256 + threadIdx.x;   // 0..65535 = (token,head)
    const int tok = id >> 5;
    const int h = id & 31;
    const int s = tok & (SEQ - 1);
    bf16x2* qp = (bf16x2*)(qkv + (size_t)tok * QKV_N + h * HDIM);
    bf16x2* kp = (bf16x2*)(qkv + (size_t)tok * QKV_N + EMBED + h * HDIM);
    for (int i = 0; i < 32; ++i) {
        const float inv = 1.0f / powf(500000.0f, (float)i * (1.0f / 32.0f));
        const float ang = (float)s * inv;
        float sn, cs;
        sincosf(ang, &sn, &cs);
        bf16x2 q = qp[i], k = kp[i];
        const float q0 = (float)q[0], q1 = (float)q[1];
        const float k0 = (float)k[0], k1 = (float)k[1];
        q[0] = (bf16_t)(q0 * cs - q1 * sn); q[1] = (bf16_t)(q0 * sn + q1 * cs);
        k[0] = (bf16_t)(k0 * cs - k1 * sn); k[1] = (bf16_t)(k0 * sn + k1 * cs);
        qp[i] = q; kp[i] = k;
    }
}

// ---------------------------------------------------------------------------
// Tile-sparse attention. One wave per (qtile=16 queries, head, batch).
// Pass1: QK^T tile maxima (causal). Select top-12 tiles/query (+own).
// Pass2: online softmax over selected tiles, PV via fp32 FMA.
// ---------------------------------------------------------------------------
__global__ __launch_bounds__(64) void attn_sparse(
    const bf16_t* __restrict__ qkv, bf16_t* __restrict__ attn)
{
    const int qt = blockIdx.x;   // 0..63 query tile
    const int h  = blockIdx.y;   // head
    const int b  = blockIdx.z;   // batch
    const int lane = threadIdx.x;
    const int quad = lane >> 4, l15 = lane & 15;

    __shared__ float tilemax[16][65];
    __shared__ unsigned long long qmask[16];
    __shared__ unsigned long long umask_s;
    __shared__ float Plds[16][17];
    __shared__ __align__(16) float Vlds[16][68];
    __shared__ float alpha_l[16];
    __shared__ float l_l[16];

    const int tok0 = b * SEQ + qt * 16;
    const bf16_t* qbase = qkv + (size_t)(tok0 + l15) * QKV_N + h * HDIM + quad * 8;
    const bf16x8 qf0 = *(const bf16x8*)qbase;
    const bf16x8 qf1 = *(const bf16x8*)(qbase + 32);

    const bf16_t* kcol = qkv + EMBED + h * HDIM + quad * 8;

    // ---- pass 1: tile maxima ----
    for (int t = 0; t <= qt; ++t) {
        const bf16_t* kb = kcol + (size_t)(b * SEQ + t * 16 + l15) * QKV_N;
        const bf16x8 kf0 = *(const bf16x8*)kb;
        const bf16x8 kf1 = *(const bf16x8*)(kb + 32);
        f32x4 sc = {0.f, 0.f, 0.f, 0.f};
        sc = __builtin_amdgcn_mfma_f32_16x16x32_bf16(qf0, kf0, sc, 0, 0, 0);
        sc = __builtin_amdgcn_mfma_f32_16x16x32_bf16(qf1, kf1, sc, 0, 0, 0);
#pragma unroll
        for (int r = 0; r < 4; ++r) {
            const int qr = quad * 4 + r;
            float v = sc[r] * 0.125f;
            if (t == qt && l15 > qr) v = -3.0e38f;   // causal within own tile
            v = fmaxf(v, __shfl_xor(v, 1));
            v = fmaxf(v, __shfl_xor(v, 2));
            v = fmaxf(v, __shfl_xor(v, 4));
            v = fmaxf(v, __shfl_xor(v, 8));
            if (l15 == 0) tilemax[qr][t] = v;
        }
    }
    __syncthreads();

    // ---- selection: top-12 (strict >, earliest index on ties) + own ----
    if (lane < 16) {
        unsigned long long m = 0;
        const int cnt = qt + 1;
        if (cnt <= 12) {
            m = (1ull << cnt) - 1ull;    // all valid tiles; NEG tiles beyond are causally dead
        } else {
            for (int it = 0; it < 12; ++it) {
                float best = -3.9e38f; int bi = 0;
                for (int t = 0; t <= qt; ++t) {
                    if ((m >> t) & 1ull) continue;
                    const float v = tilemax[lane][t];
                    if (v > best) { best = v; bi = t; }
                }
                m |= 1ull << bi;
            }
        }
        m |= 1ull << qt;                 // own tile always allowed
        qmask[lane] = m;
    }
    __syncthreads();
    if (lane == 0) {
        unsigned long long u = 0;
#pragma unroll
        for (int q2 = 0; q2 < 16; ++q2) u |= qmask[q2];
        umask_s = u;
    }
    __syncthreads();
    unsigned long long myrow[4];
#pragma unroll
    for (int r = 0; r < 4; ++r) myrow[r] = qmask[quad * 4 + r];
    const unsigned long long un = umask_s;

    float m_run[4], l_run[4];
#pragma unroll
    for (int r = 0; r < 4; ++r) { m_run[r] = -3.0e38f; l_run[r] = 0.f; }
    float o[16];
#pragma unroll
    for (int e = 0; e < 16; ++e) o[e] = 0.f;

    const bf16_t* vcol = qkv + 2 * EMBED + h * HDIM;

    // ---- pass 2: online softmax + PV over selected tiles ----
    for (int t = 0; t <= qt; ++t) {
        if (!((un >> t) & 1ull)) continue;     // uniform across block
        __syncthreads();
        {   // stage V tile as fp32
            const bf16_t* vb = vcol + (size_t)(b * SEQ + t * 16 + l15) * QKV_N + quad * 16;
            const bf16x8 v0 = *(const bf16x8*)vb;
            const bf16x8 v1 = *(const bf16x8*)(vb + 8);
#pragma unroll
            for (int e = 0; e < 8; ++e) {
                Vlds[l15][quad * 16 + e]     = (float)v0[e];
                Vlds[l15][quad * 16 + 8 + e] = (float)v1[e];
            }
        }
        const bf16_t* kb = kcol + (size_t)(b * SEQ + t * 16 + l15) * QKV_N;
        const bf16x8 kf0 = *(const bf16x8*)kb;
        const bf16x8 kf1 = *(const bf16x8*)(kb + 32);
        f32x4 sc = {0.f, 0.f, 0.f, 0.f};
        sc = __builtin_amdgcn_mfma_f32_16x16x32_bf16(qf0, kf0, sc, 0, 0, 0);
        sc = __builtin_amdgcn_mfma_f32_16x16x32_bf16(qf1, kf1, sc, 0, 0, 0);
#pragma unroll
        for (int r = 0; r < 4; ++r) {
            const int qr = quad * 4 + r;
            const bool ok = ((myrow[r] >> t) & 1ull) && (t < qt || l15 <= qr);
            const float sv = ok ? sc[r] * 0.125f : -3.0e38f;
            float mt = sv;
            mt = fmaxf(mt, __shfl_xor(mt, 1));
            mt = fmaxf(mt, __shfl_xor(mt, 2));
            mt = fmaxf(mt, __shfl_xor(mt, 4));
            mt = fmaxf(mt, __shfl_xor(mt, 8));
            const float mn = fmaxf(m_run[r], mt);
            const float al = __expf(m_run[r] - mn);
            const float pv = ok ? __expf(sv - mn) : 0.f;  // explicit 0: avoids exp(0) trap
            float rsum = pv;
            rsum += __shfl_xor(rsum, 1);
            rsum += __shfl_xor(rsum, 2);
            rsum += __shfl_xor(rsum, 4);
            rsum += __shfl_xor(rsum, 8);
            l_run[r] = l_run[r] * al + rsum;
            m_run[r] = mn;
            Plds[qr][l15] = pv;
            if (l15 == 0) alpha_l[qr] = al;
        }
        __syncthreads();
        const float aq = alpha_l[l15];
#pragma unroll
        for (int e = 0; e < 16; ++e) o[e] *= aq;
#pragma unroll
        for (int k = 0; k < 16; ++k) {
            const float pk = Plds[l15][k];
            const float4* vr = (const float4*)&Vlds[k][quad * 16];
            const float4 va = vr[0], vb2 = vr[1], vc2 = vr[2], vd = vr[3];
            o[0]  += pk * va.x;  o[1]  += pk * va.y;  o[2]  += pk * va.z;  o[3]  += pk * va.w;
            o[4]  += pk * vb2.x; o[5]  += pk * vb2.y; o[6]  += pk * vb2.z; o[7]  += pk * vb2.w;
            o[8]  += pk * vc2.x; o[9]  += pk * vc2.y; o[10] += pk * vc2.z; o[11] += pk * vc2.w;
            o[12] += pk * vd.x;  o[13] += pk * vd.y;  o[14] += pk * vd.z;  o[15] += pk * vd.w;
        }
    }
    if (l15 == 0) {
#pragma unroll
        for (int r = 0; r < 4; ++r) l_l[quad * 4 + r] = l_run[r];
    }
    __syncthreads();
    const float inv = 1.0f / l_l[l15];
    bf16_t* op = attn + (size_t)(tok0 + l15) * EMBED + h * HDIM + quad * 16;
    bf16x8 o0, o1;
#pragma unroll
    for (int e = 0; e < 8; ++e) {
        o0[e] = (bf16_t)(o[e] * inv);
        o1[e] = (bf16_t)(o[8 + e] * inv);
    }
    *(bf16x8*)op = o0;
    *(bf16x8*)(op + 8) = o1;
}

// ---------------------------------------------------------------------------
// Workspace layout (120 MB peak, lifetime-overlaid):
//   [0,32M)     Wt region: wqkv_t(24M) / wo_t(8M) / wg_t(32M) / wu_t(32M) / wd_t(32M), serial reuse
//   [32M,64M)   qkv(24M)+attnb(8M)  -> later gate(32M)
//   [64M,80M)   x1 fp32 (16M)
//   [80M,88M)   nbuf / n2 (8M)
//   [88M,120M)  hbuf (32M)
// ---------------------------------------------------------------------------
extern "C" void kernel_launch(void* const* d_in, const int* in_sizes, int n_in,
                              void* d_out, int out_size, void* d_ws, size_t ws_size,
                              hipStream_t stream)
{
    const float* x   = (const float*)d_in[0];
    const float* ans = (const float*)d_in[1];
    const float* wq  = (const float*)d_in[2];
    const float* wk  = (const float*)d_in[3];
    const float* wv  = (const float*)d_in[4];
    const float* wo  = (const float*)d_in[5];
    const float* fns = (const float*)d_in[6];
    const float* wg  = (const float*)d_in[7];
    const float* wu  = (const float*)d_in[8];
    const float* wd  = (const float*)d_in[9];
    (void)in_sizes; (void)n_in; (void)out_size; (void)ws_size;

    char* ws = (char*)d_ws;
    const size_t MB = 1024 * 1024;
    bf16_t* wt_reg = (bf16_t*)(ws);             // 32 MB weight region
    bf16_t* qkv    = (bf16_t*)(ws + 32 * MB);   // 24 MB
    bf16_t* attnb  = (bf16_t*)(ws + 56 * MB);   // 8 MB
    bf16_t* gate   = (bf16_t*)(ws + 32 * MB);   // 32 MB (overlays dead qkv+attnb)
    float*  x1     = (float* )(ws + 64 * MB);   // 16 MB
    bf16_t* nbuf   = (bf16_t*)(ws + 80 * MB);   // 8 MB (also n2)
    bf16_t* hbuf   = (bf16_t*)(ws + 88 * MB);   // 32 MB

    // ---- attention phase ----
    transpose_cvt<<<dim3(64, 64), 256, 0, stream>>>(wq, wt_reg,                             EMBED, EMBED);
    transpose_cvt<<<dim3(64, 64), 256, 0, stream>>>(wk, wt_reg + (size_t)EMBED * EMBED,     EMBED, EMBED);
    transpose_cvt<<<dim3(64, 64), 256, 0, stream>>>(wv, wt_reg + (size_t)2 * EMBED * EMBED, EMBED, EMBED);
    rmsnorm_bf16<<<NTOK, 256, 0, stream>>>(x, ans, nbuf);
    gemm_bt<0><<<dim3(16, 48), 256, 0, stream>>>(nbuf, wt_reg, qkv, nullptr, nullptr, NTOK, QKV_N, EMBED);
    rope_qk<<<256, 256, 0, stream>>>(qkv);
    attn_sparse<<<dim3(64, 32, 2), 64, 0, stream>>>(qkv, attnb);
    transpose_cvt<<<dim3(64, 64), 256, 0, stream>>>(wo, wt_reg, EMBED, EMBED);   // wqkv_t dead
    gemm_bt<1><<<dim3(16, 16), 256, 0, stream>>>(attnb, wt_reg, x1, x, nullptr, NTOK, EMBED, EMBED);

    // ---- MLP phase ----
    rmsnorm_bf16<<<NTOK, 256, 0, stream>>>(x1, fns, nbuf);                       // n2
    transpose_cvt<<<dim3(256, 64), 256, 0, stream>>>(wg, wt_reg, EMBED, MLP);    // wo_t dead
    gemm_bt<0><<<dim3(16, 64), 256, 0, stream>>>(nbuf, wt_reg, gate, nullptr, nullptr, NTOK, MLP, EMBED);
    transpose_cvt<<<dim3(256, 64), 256, 0, stream>>>(wu, wt_reg, EMBED, MLP);    // wg_t dead
    gemm_bt<2><<<dim3(16, 64), 256, 0, stream>>>(nbuf, wt_reg, hbuf, nullptr, gate, NTOK, MLP, EMBED);
    transpose_cvt<<<dim3(64, 256), 256, 0, stream>>>(wd, wt_reg, MLP, EMBED);    // wu_t dead
    gemm_bt<1><<<dim3(16, 16), 256, 0, stream>>>(hbuf, wt_reg, (float*)d_out, x1, nullptr, NTOK, EMBED, MLP);
}